// Round 8
// baseline (593.361 us; speedup 1.0000x reference)
//
#include <hip/hip_runtime.h>
#include <stdint.h>

// ---------------------------------------------------------------------------
// BondMatrixMessage: messages[b,e,i] = sum_{k,j} bond[b,e,k] W[k,i,j] src[b,e,j]
// GEMM recast: C[16384 x 64] = A[16384 x 4096] @ W2[4096 x 64]
//   A[e, k*64+j] = bond[e,k]*src[e,j]  (registers, v_pk_mul_f16)
//   W2 prep-cast to f16 in MFMA-fragment order (w2f) by prep kernel.
// R8: HERD-DEPHASING + REPS=8 DIAGNOSTIC.
// R3/R6/R7 (ds_read ring / register ring / gll+counted-vmcnt) all gave the
// same ~19 us bond_msg => bound is what they share: all 256 blocks walk the
// same 512 KB w2f in the same order in lockstep -> per-XCD L2 bank herding.
// Fix: per-block phase rotation (kq' quarter rotation + q0 k-chunk rotation,
// address-level only; register indices stay compile-time). REPS=8 with
// runtime-true re-zero (R4-proven) to surface real counters in the top-5.
// conn is int32 (harness narrows int64): src idx = conn[e*2].
// ---------------------------------------------------------------------------

#define NATOMS 256
#define DIM 64
#define BM 64
#define REPS 8   // diagnostic repeat; 1 for production

typedef _Float16 f16;
typedef _Float16 f16x2 __attribute__((ext_vector_type(2)));
typedef _Float16 f16x8 __attribute__((ext_vector_type(8)));
typedef float f32x16 __attribute__((ext_vector_type(16)));

#define AS1 __attribute__((address_space(1)))
#define AS3 __attribute__((address_space(3)))

union H8 { f16x8 v8; f16x2 v2[4]; };

static __device__ __forceinline__ void gll16(const void* g, void* l) {
    __builtin_amdgcn_global_load_lds((AS1 void*)(uintptr_t)g, (AS3 void*)l, 16, 0, 0);
}

// prep: cast + permute bt (64 x 4096 f32) into fragment-ordered f16 chunks.
// Chunk (kg, wc, s, l): bt[kg][i*64 + u*8 .. +8], i=(l&31)+32*wc, u=2*s+(l>>5).
__global__ __launch_bounds__(256) void prep_w2f(const float* __restrict__ bt,
                                                f16* __restrict__ w2f) {
    const int d  = blockIdx.x * 256 + threadIdx.x;   // 32768 chunks
    const int kg = d >> 9, c = d & 511;
    const int wcq = c >> 8, s = (c >> 6) & 3, l = c & 63;
    const int i = (l & 31) + 32 * wcq;
    const int u = 2 * s + (l >> 5);
    const float* src = bt + (size_t)kg * 4096 + i * 64 + u * 8;
    const float4 p = *reinterpret_cast<const float4*>(src);
    const float4 q = *reinterpret_cast<const float4*>(src + 4);
    const f16x8 h = { (f16)p.x, (f16)p.y, (f16)p.z, (f16)p.w,
                      (f16)q.x, (f16)q.y, (f16)q.z, (f16)q.w };
    reinterpret_cast<f16x8*>(w2f)[d] = h;
}

static __device__ __forceinline__ unsigned swz16(unsigned lane) {
    return (lane * 16u) ^ ((lane & 0x38u) << 1);
}

__global__ __launch_bounds__(512, 2) void bond_msg(
    const float* __restrict__ atom, const float* __restrict__ bond,
    const int* __restrict__ conn, const f16* __restrict__ w2f,
    float* __restrict__ out)
{
    // LDS: main loop: [w*16K, w*16K+16K) = wave w's 4 x 4KB stage buffers.
    //      epilogue (after barrier): [w*8K, w*8K+8K) partials, swizzled.
    __shared__ __align__(16) unsigned char smem[131072];

    const int tid  = threadIdx.x;
    const int lane = tid & 63;
    const int w    = tid >> 6;     // wave 0..7
    const int wc   = w & 1;        // column half (i: 0-31 / 32-63)
    const int kq   = w >> 1;       // physical k-quarter id
    const int lo   = lane & 31;
    const int hi   = lane >> 5;
    const int blk  = blockIdx.x;
    const int bond0 = blk * BM;    // 8 blocks per batch; never straddles

    // ---- herd-dephasing rotations (within-XCD blocks get distinct phases;
    // XCD = blk&7 under round-robin dispatch, so derive phases from blk>>3)
    const int kqr  = (kq + (blk >> 5)) & 3;   // logical k-quarter of this wave
    const int q0   = (blk >> 3) & 3;          // k-chunk rotation (x4 iters)
    const int rot4 = q0 * 4;

    // ---- prologue global loads
    const int m0 = lo, m1 = lo + 32;
    const int ia0 = conn[(bond0 + m0) * 2];
    const int ia1 = conn[(bond0 + m1) * 2];

    const char* gw = reinterpret_cast<const char*>(w2f)
                   + (size_t)(kqr * 16) * 8192 + wc * 4096 + lane * 16;
    char* lsta = reinterpret_cast<char*>(smem) + w * 16384;          // uniform
    const char* lread = reinterpret_cast<const char*>(smem) + w * 16384 + lane * 16;

    #define ISSUE(itf) do {                                               \
        const char* _g = gw + (((itf) + rot4) & 15) * 8192;               \
        char* _l = lsta + ((itf) & 3) * 4096;                             \
        gll16(_g,        _l);                                             \
        gll16(_g + 1024, _l + 1024);                                      \
        gll16(_g + 2048, _l + 2048);                                      \
        gll16(_g + 3072, _l + 3072);                                      \
    } while (0)

    // ---- bond k-slices -> dup'd f16 pairs, PRE-ROTATED so bp[iti] matches
    // the k-chunk ((iti>>2)+q0)&3 that iteration iti's buffer holds.
    f16x2 bp0[16], bp1[16];
    {
        const float* br0 = bond + (size_t)(bond0 + m0) * DIM + kqr * 16;
        const float* br1 = bond + (size_t)(bond0 + m1) * DIM + kqr * 16;
        #pragma unroll
        for (int q = 0; q < 4; ++q) {
            const int qs = ((q + q0) & 3) * 4;
            const float4 v0 = *reinterpret_cast<const float4*>(br0 + qs);
            const float4 v1 = *reinterpret_cast<const float4*>(br1 + qs);
            const f16 a0 = (f16)v0.x, a1 = (f16)v0.y, a2 = (f16)v0.z, a3 = (f16)v0.w;
            const f16 c0 = (f16)v1.x, c1 = (f16)v1.y, c2 = (f16)v1.z, c3 = (f16)v1.w;
            bp0[q*4+0] = (f16x2){a0,a0}; bp0[q*4+1] = (f16x2){a1,a1};
            bp0[q*4+2] = (f16x2){a2,a2}; bp0[q*4+3] = (f16x2){a3,a3};
            bp1[q*4+0] = (f16x2){c0,c0}; bp1[q*4+1] = (f16x2){c1,c1};
            bp1[q*4+2] = (f16x2){c2,c2}; bp1[q*4+3] = (f16x2){c3,c3};
        }
    }

    // ---- src atom gather -> registers (f16 pairs)
    const float* ar0 = atom + (size_t)(blk >> 3) * (NATOMS * DIM) + (size_t)ia0 * DIM;
    const float* ar1 = atom + (size_t)(blk >> 3) * (NATOMS * DIM) + (size_t)ia1 * DIM;
    f16x2 srcv[2][4][4];   // [m-frag][s][pair]; j = s*16 + hi*8 + {0..7}
    #pragma unroll
    for (int s = 0; s < 4; ++s) {
        const int j0 = s * 16 + hi * 8;
        float4 p0 = *reinterpret_cast<const float4*>(ar0 + j0);
        float4 p1 = *reinterpret_cast<const float4*>(ar0 + j0 + 4);
        float4 q0v = *reinterpret_cast<const float4*>(ar1 + j0);
        float4 q1v = *reinterpret_cast<const float4*>(ar1 + j0 + 4);
        srcv[0][s][0] = (f16x2){ (f16)p0.x, (f16)p0.y };
        srcv[0][s][1] = (f16x2){ (f16)p0.z, (f16)p0.w };
        srcv[0][s][2] = (f16x2){ (f16)p1.x, (f16)p1.y };
        srcv[0][s][3] = (f16x2){ (f16)p1.z, (f16)p1.w };
        srcv[1][s][0] = (f16x2){ (f16)q0v.x, (f16)q0v.y };
        srcv[1][s][1] = (f16x2){ (f16)q0v.z, (f16)q0v.w };
        srcv[1][s][2] = (f16x2){ (f16)q1v.x, (f16)q1v.y };
        srcv[1][s][3] = (f16x2){ (f16)q1v.z, (f16)q1v.w };
    }

    // ---- main loop: per-wave counted vmcnt pipeline, REPS repeats
    f32x16 acc0 = {}, acc1 = {};
    const bool opq = (ia0 > -2000000000);   // runtime-true: defeats rep DCE

    #define COMPIT(iti) do {                                              \
        const char* _lr = lread + ((iti) & 3) * 4096;                     \
        const f16x2 _c0 = bp0[iti];                                       \
        const f16x2 _c1 = bp1[iti];                                       \
        _Pragma("unroll")                                                 \
        for (int s = 0; s < 4; ++s) {                                     \
            const f16x8 bf = *reinterpret_cast<const f16x8*>(_lr + s * 1024); \
            H8 _a0, _a1;                                                  \
            _Pragma("unroll")                                             \
            for (int t = 0; t < 4; ++t) {                                 \
                _a0.v2[t] = _c0 * srcv[0][s][t];                          \
                _a1.v2[t] = _c1 * srcv[1][s][t];                          \
            }                                                             \
            acc0 = __builtin_amdgcn_mfma_f32_32x32x16_f16(_a0.v8, bf, acc0, 0, 0, 0); \
            acc1 = __builtin_amdgcn_mfma_f32_32x32x16_f16(_a1.v8, bf, acc1, 0, 0, 0); \
        }                                                                 \
    } while (0)

    #define STEP(iti, wtxt) do {                                          \
        if ((iti) + 3 < 16) ISSUE((iti) + 3);                             \
        asm volatile("s_waitcnt vmcnt(" wtxt ")" ::: "memory");           \
        __builtin_amdgcn_sched_barrier(0);                                \
        COMPIT(iti);                                                      \
    } while (0)

    for (int rep = 0; rep < REPS; ++rep) {
        if (opq) { acc0 = (f32x16){}; acc1 = (f32x16){}; }
        ISSUE(0); ISSUE(1); ISSUE(2);
        STEP( 0, "12"); STEP( 1, "12"); STEP( 2, "12"); STEP( 3, "12");
        STEP( 4, "12"); STEP( 5, "12"); STEP( 6, "12"); STEP( 7, "12");
        STEP( 8, "12"); STEP( 9, "12"); STEP(10, "12"); STEP(11, "12");
        STEP(12, "12"); STEP(13, "8");  STEP(14, "4");  STEP(15, "0");
    }

    #undef STEP
    #undef COMPIT
    #undef ISSUE

    // ---- epilogue: barrier (LDS reuse), partial stores (swizzled),
    // barrier, 512-thread parallel reduce + coalesced write.
    // Note: physical wave w holds logical quarter kqr (bijection per block),
    // so summing all 4 slots with matching wc covers all quarters.
    __syncthreads();
    {
        const unsigned wbase = (unsigned)w * 8192u;
        const unsigned so = swz16((unsigned)lane);
        #pragma unroll
        for (int g = 0; g < 4; ++g) {
            float4 v0 = { acc0[4*g+0], acc0[4*g+1], acc0[4*g+2], acc0[4*g+3] };
            *reinterpret_cast<float4*>(smem + wbase + g*1024 + so) = v0;
            float4 v1 = { acc1[4*g+0], acc1[4*g+1], acc1[4*g+2], acc1[4*g+3] };
            *reinterpret_cast<float4*>(smem + wbase + (g+4)*1024 + so) = v1;
        }
    }
    __syncthreads();
    {
        const int c  = tid & 63;
        const int rb = tid >> 6;
        const int a  = rb >> 2, g = rb & 3;
        const unsigned colb = (unsigned)(c & 31);
        const unsigned wcs  = (unsigned)(c >> 5);
        const unsigned o0 = swz16(colb);
        const unsigned o1 = swz16(32u + colb);
        float4 s0 = {0.f,0.f,0.f,0.f}, s1 = {0.f,0.f,0.f,0.f};
        #pragma unroll
        for (int q = 0; q < 4; ++q) {
            const unsigned base = (unsigned)((q*2 + wcs) * 8192 + (a*4+g) * 1024);
            const float4 u0 = *reinterpret_cast<const float4*>(smem + base + o0);
            const float4 u1 = *reinterpret_cast<const float4*>(smem + base + o1);
            s0.x += u0.x; s0.y += u0.y; s0.z += u0.z; s0.w += u0.w;
            s1.x += u1.x; s1.y += u1.y; s1.z += u1.z; s1.w += u1.w;
        }
        float* orow = out + (size_t)(bond0 + 32*a + 8*g) * 64 + c;
        orow[0*64] = s0.x; orow[1*64] = s0.y; orow[2*64] = s0.z; orow[3*64] = s0.w;
        orow[4*64] = s1.x; orow[5*64] = s1.y; orow[6*64] = s1.z; orow[7*64] = s1.w;
    }
}

// ---- fallback (ws too small): f32, LDS-staged, correct.
__global__ __launch_bounds__(256) void bond_fallback(
    const float* __restrict__ atom, const float* __restrict__ bond,
    const int* __restrict__ conn, const float* __restrict__ bt,
    float* __restrict__ out)
{
    __shared__ float Wk[4096];
    __shared__ float srcs[4][64];
    __shared__ float bnds[4][64];
    const int blk = blockIdx.x;
    const int e0 = blk * 4;
    const int b = e0 >> 9;
    const int t = threadIdx.x;
    const int il = t & 63, eg = t >> 6;
    const int e = e0 + eg;
    const int ia = conn[e * 2];
    srcs[eg][il] = atom[(size_t)b * (NATOMS * DIM) + (size_t)ia * DIM + il];
    bnds[eg][il] = bond[(size_t)e * DIM + il];
    float acc = 0.f;
    for (int k = 0; k < 64; ++k) {
        __syncthreads();
        #pragma unroll
        for (int c = 0; c < 4; ++c) {
            float4 v = reinterpret_cast<const float4*>(bt + (size_t)k * 4096)[t + c * 256];
            reinterpret_cast<float4*>(Wk)[t + c * 256] = v;
        }
        __syncthreads();
        float s = 0.f;
        #pragma unroll
        for (int j = 0; j < 64; ++j) s += Wk[il * 64 + j] * srcs[eg][j];
        acc += bnds[eg][k] * s;
    }
    out[(size_t)e * DIM + il] = acc;
}

extern "C" void kernel_launch(void* const* d_in, const int* in_sizes, int n_in,
                              void* d_out, int out_size, void* d_ws, size_t ws_size,
                              hipStream_t stream) {
    const float* atom = (const float*)d_in[0];   // (32,256,64) f32
    const float* bond = (const float*)d_in[1];   // (32,512,64) f32
    const int*   conn = (const int*)d_in[2];     // (32,512,2) int32 (narrowed)
    const float* bt   = (const float*)d_in[3];   // (64,4096) f32
    float* out = (float*)d_out;                  // (32,512,64) f32

    if (ws_size >= (size_t)64 * 4096 * sizeof(f16)) {
        f16* w2f = (f16*)d_ws;                   // 512 KB scratch
        prep_w2f<<<128, 256, 0, stream>>>(bt, w2f);
        bond_msg<<<256, 512, 0, stream>>>(atom, bond, conn, w2f, out);
    } else {
        bond_fallback<<<4096, 256, 0, stream>>>(atom, bond, conn, bt, out);
    }
}

// Round 9
// 51.527 us; speedup vs baseline: 11.5157x; 11.5157x over previous
//
#include <hip/hip_runtime.h>
#include <stdint.h>

// ---------------------------------------------------------------------------
// BondMatrixMessage: messages[b,e,i] = sum_{k,j} bond[b,e,k] W[k,i,j] src[b,e,j]
// GEMM recast: C[16384 x 64] = A[16384 x 4096] @ W2[4096 x 64]
//   A[e, k*64+j] = bond[e,k]*src[e,j]  (registers, v_pk_mul_f16)
//   W2 prep-cast to f16 in MFMA-fragment order (w2f) by prep kernel.
// R9: MEASUREMENT ROUND. Kernel is byte-identical to R7 (gll 4-buffer
// pipeline, hand-counted vmcnt, no herd rotation -- R8's rotation caused
// catastrophic scratch spill and is reverted). kernel_launch launches
// bond_msg THREE times (idempotent, identical output). Total-time delta vs
// R7 (24.25 us) = 2 x (hot bond_msg + launch gap), discriminating
// hot-loop-bound (~60 us) vs cold/overhead-bound (~40 us) hypotheses.
// conn is int32 (harness narrows int64): src idx = conn[e*2].
// ---------------------------------------------------------------------------

#define NATOMS 256
#define DIM 64
#define BM 64

typedef _Float16 f16;
typedef _Float16 f16x2 __attribute__((ext_vector_type(2)));
typedef _Float16 f16x8 __attribute__((ext_vector_type(8)));
typedef float f32x16 __attribute__((ext_vector_type(16)));

#define AS1 __attribute__((address_space(1)))
#define AS3 __attribute__((address_space(3)))

union H8 { f16x8 v8; f16x2 v2[4]; };

static __device__ __forceinline__ void gll16(const void* g, void* l) {
    __builtin_amdgcn_global_load_lds((AS1 void*)(uintptr_t)g, (AS3 void*)l, 16, 0, 0);
}

// prep: cast + permute bt (64 x 4096 f32) into fragment-ordered f16 chunks.
// Chunk (kg, wc, s, l): bt[kg][i*64 + u*8 .. +8], i=(l&31)+32*wc, u=2*s+(l>>5).
__global__ __launch_bounds__(256) void prep_w2f(const float* __restrict__ bt,
                                                f16* __restrict__ w2f) {
    const int d  = blockIdx.x * 256 + threadIdx.x;   // 32768 chunks
    const int kg = d >> 9, c = d & 511;
    const int wcq = c >> 8, s = (c >> 6) & 3, l = c & 63;
    const int i = (l & 31) + 32 * wcq;
    const int u = 2 * s + (l >> 5);
    const float* src = bt + (size_t)kg * 4096 + i * 64 + u * 8;
    const float4 p = *reinterpret_cast<const float4*>(src);
    const float4 q = *reinterpret_cast<const float4*>(src + 4);
    const f16x8 h = { (f16)p.x, (f16)p.y, (f16)p.z, (f16)p.w,
                      (f16)q.x, (f16)q.y, (f16)q.z, (f16)q.w };
    reinterpret_cast<f16x8*>(w2f)[d] = h;
}

static __device__ __forceinline__ unsigned swz16(unsigned lane) {
    // 16B-granular XOR swizzle for the epilogue partial buffer.
    return (lane * 16u) ^ ((lane & 0x38u) << 1);
}

__global__ __launch_bounds__(512, 2) void bond_msg(
    const float* __restrict__ atom, const float* __restrict__ bond,
    const int* __restrict__ conn, const f16* __restrict__ w2f,
    float* __restrict__ out)
{
    // LDS: main loop: [w*16K, w*16K+16K) = wave w's 4 x 4KB stage buffers.
    //      epilogue (after barrier): [w*8K, w*8K+8K) partials, swizzled.
    __shared__ __align__(16) unsigned char smem[131072];

    const int tid  = threadIdx.x;
    const int lane = tid & 63;
    const int w    = tid >> 6;     // wave 0..7
    const int wc   = w & 1;        // column half (i: 0-31 / 32-63)
    const int kq   = w >> 1;       // k quarter (16 k-values each)
    const int lo   = lane & 31;
    const int hi   = lane >> 5;
    const int blk  = blockIdx.x;
    const int bond0 = blk * BM;    // 8 blocks per batch; never straddles

    // ---- prologue global loads (issue early; conversions wait only these)
    const int m0 = lo, m1 = lo + 32;
    const int ia0 = conn[(bond0 + m0) * 2];
    const int ia1 = conn[(bond0 + m1) * 2];

    const char* gw = reinterpret_cast<const char*>(w2f)
                   + (size_t)(kq * 16) * 8192 + wc * 4096 + lane * 16;
    char* lsta = reinterpret_cast<char*>(smem) + w * 16384;          // uniform
    const char* lread = reinterpret_cast<const char*>(smem) + w * 16384 + lane * 16;

    #define ISSUE(itf) do {                                               \
        const char* _g = gw + (itf) * 8192;                               \
        char* _l = lsta + ((itf) & 3) * 4096;                             \
        gll16(_g,        _l);                                             \
        gll16(_g + 1024, _l + 1024);                                      \
        gll16(_g + 2048, _l + 2048);                                      \
        gll16(_g + 3072, _l + 3072);                                      \
    } while (0)

    // start the stage pipeline immediately (independent of everything else)
    ISSUE(0); ISSUE(1); ISSUE(2);

    // ---- bond k-slices -> dup'd f16 pairs in registers
    f16x2 bp0[16], bp1[16];
    {
        const float* br0 = bond + (size_t)(bond0 + m0) * DIM + kq * 16;
        const float* br1 = bond + (size_t)(bond0 + m1) * DIM + kq * 16;
        #pragma unroll
        for (int q = 0; q < 4; ++q) {
            const float4 v0 = *reinterpret_cast<const float4*>(br0 + q * 4);
            const float4 v1 = *reinterpret_cast<const float4*>(br1 + q * 4);
            const f16 a0 = (f16)v0.x, a1 = (f16)v0.y, a2 = (f16)v0.z, a3 = (f16)v0.w;
            const f16 c0 = (f16)v1.x, c1 = (f16)v1.y, c2 = (f16)v1.z, c3 = (f16)v1.w;
            bp0[q*4+0] = (f16x2){a0,a0}; bp0[q*4+1] = (f16x2){a1,a1};
            bp0[q*4+2] = (f16x2){a2,a2}; bp0[q*4+3] = (f16x2){a3,a3};
            bp1[q*4+0] = (f16x2){c0,c0}; bp1[q*4+1] = (f16x2){c1,c1};
            bp1[q*4+2] = (f16x2){c2,c2}; bp1[q*4+3] = (f16x2){c3,c3};
        }
    }

    // ---- src atom gather -> registers (f16 pairs)
    const float* ar0 = atom + (size_t)(blk >> 3) * (NATOMS * DIM) + (size_t)ia0 * DIM;
    const float* ar1 = atom + (size_t)(blk >> 3) * (NATOMS * DIM) + (size_t)ia1 * DIM;
    f16x2 srcv[2][4][4];   // [m-frag][s][pair]; j = s*16 + hi*8 + {0..7}
    #pragma unroll
    for (int s = 0; s < 4; ++s) {
        const int j0 = s * 16 + hi * 8;
        float4 p0 = *reinterpret_cast<const float4*>(ar0 + j0);
        float4 p1 = *reinterpret_cast<const float4*>(ar0 + j0 + 4);
        float4 q0 = *reinterpret_cast<const float4*>(ar1 + j0);
        float4 q1 = *reinterpret_cast<const float4*>(ar1 + j0 + 4);
        srcv[0][s][0] = (f16x2){ (f16)p0.x, (f16)p0.y };
        srcv[0][s][1] = (f16x2){ (f16)p0.z, (f16)p0.w };
        srcv[0][s][2] = (f16x2){ (f16)p1.x, (f16)p1.y };
        srcv[0][s][3] = (f16x2){ (f16)p1.z, (f16)p1.w };
        srcv[1][s][0] = (f16x2){ (f16)q0.x, (f16)q0.y };
        srcv[1][s][1] = (f16x2){ (f16)q0.z, (f16)q0.w };
        srcv[1][s][2] = (f16x2){ (f16)q1.x, (f16)q1.y };
        srcv[1][s][3] = (f16x2){ (f16)q1.z, (f16)q1.w };
    }

    // ---- main loop: 16 fully-unrolled steps, per-wave counted vmcnt
    f32x16 acc0 = {}, acc1 = {};

    #define COMPIT(iti) do {                                              \
        const char* _lr = lread + ((iti) & 3) * 4096;                     \
        const f16x2 _c0 = bp0[iti];                                       \
        const f16x2 _c1 = bp1[iti];                                       \
        _Pragma("unroll")                                                 \
        for (int s = 0; s < 4; ++s) {                                     \
            const f16x8 bf = *reinterpret_cast<const f16x8*>(_lr + s * 1024); \
            H8 _a0, _a1;                                                  \
            _Pragma("unroll")                                             \
            for (int t = 0; t < 4; ++t) {                                 \
                _a0.v2[t] = _c0 * srcv[0][s][t];                          \
                _a1.v2[t] = _c1 * srcv[1][s][t];                          \
            }                                                             \
            acc0 = __builtin_amdgcn_mfma_f32_32x32x16_f16(_a0.v8, bf, acc0, 0, 0, 0); \
            acc1 = __builtin_amdgcn_mfma_f32_32x32x16_f16(_a1.v8, bf, acc1, 0, 0, 0); \
        }                                                                 \
    } while (0)

    // STEP(it): issue it+3 (if any), wait buf[it] complete (counted), compute.
    #define STEP(iti, wtxt) do {                                          \
        if ((iti) + 3 < 16) ISSUE((iti) + 3);                             \
        asm volatile("s_waitcnt vmcnt(" wtxt ")" ::: "memory");           \
        __builtin_amdgcn_sched_barrier(0);                                \
        COMPIT(iti);                                                      \
    } while (0)

    STEP( 0, "12"); STEP( 1, "12"); STEP( 2, "12"); STEP( 3, "12");
    STEP( 4, "12"); STEP( 5, "12"); STEP( 6, "12"); STEP( 7, "12");
    STEP( 8, "12"); STEP( 9, "12"); STEP(10, "12"); STEP(11, "12");
    STEP(12, "12"); STEP(13, "8");  STEP(14, "4");  STEP(15, "0");

    #undef STEP
    #undef COMPIT
    #undef ISSUE

    // ---- epilogue: barrier (LDS reuse), all waves store partials
    // (swizzled, conflict-free), barrier, 512-thread parallel reduce+write.
    __syncthreads();
    {
        const unsigned wbase = (unsigned)w * 8192u;
        const unsigned so = swz16((unsigned)lane);
        #pragma unroll
        for (int g = 0; g < 4; ++g) {
            float4 v0 = { acc0[4*g+0], acc0[4*g+1], acc0[4*g+2], acc0[4*g+3] };
            *reinterpret_cast<float4*>(smem + wbase + g*1024 + so) = v0;
            float4 v1 = { acc1[4*g+0], acc1[4*g+1], acc1[4*g+2], acc1[4*g+3] };
            *reinterpret_cast<float4*>(smem + wbase + (g+4)*1024 + so) = v1;
        }
    }
    __syncthreads();
    {
        // thread t: column c = t&63, row group rb = t>>6 -> rows 32a+8g+{0..7}
        const int c  = tid & 63;
        const int rb = tid >> 6;
        const int a  = rb >> 2, g = rb & 3;
        const unsigned colb = (unsigned)(c & 31);
        const unsigned wcs  = (unsigned)(c >> 5);
        const unsigned o0 = swz16(colb);        // hi=0 lane = colb
        const unsigned o1 = swz16(32u + colb);  // hi=1 lane
        float4 s0 = {0.f,0.f,0.f,0.f}, s1 = {0.f,0.f,0.f,0.f};
        #pragma unroll
        for (int q = 0; q < 4; ++q) {
            const unsigned base = (unsigned)((q*2 + wcs) * 8192 + (a*4+g) * 1024);
            const float4 u0 = *reinterpret_cast<const float4*>(smem + base + o0);
            const float4 u1 = *reinterpret_cast<const float4*>(smem + base + o1);
            s0.x += u0.x; s0.y += u0.y; s0.z += u0.z; s0.w += u0.w;
            s1.x += u1.x; s1.y += u1.y; s1.z += u1.z; s1.w += u1.w;
        }
        float* orow = out + (size_t)(bond0 + 32*a + 8*g) * 64 + c;
        orow[0*64] = s0.x; orow[1*64] = s0.y; orow[2*64] = s0.z; orow[3*64] = s0.w;
        orow[4*64] = s1.x; orow[5*64] = s1.y; orow[6*64] = s1.z; orow[7*64] = s1.w;
    }
}

// ---- fallback (ws too small): f32, LDS-staged, correct.
__global__ __launch_bounds__(256) void bond_fallback(
    const float* __restrict__ atom, const float* __restrict__ bond,
    const int* __restrict__ conn, const float* __restrict__ bt,
    float* __restrict__ out)
{
    __shared__ float Wk[4096];
    __shared__ float srcs[4][64];
    __shared__ float bnds[4][64];
    const int blk = blockIdx.x;
    const int e0 = blk * 4;
    const int b = e0 >> 9;
    const int t = threadIdx.x;
    const int il = t & 63, eg = t >> 6;
    const int e = e0 + eg;
    const int ia = conn[e * 2];
    srcs[eg][il] = atom[(size_t)b * (NATOMS * DIM) + (size_t)ia * DIM + il];
    bnds[eg][il] = bond[(size_t)e * DIM + il];
    float acc = 0.f;
    for (int k = 0; k < 64; ++k) {
        __syncthreads();
        #pragma unroll
        for (int c = 0; c < 4; ++c) {
            float4 v = reinterpret_cast<const float4*>(bt + (size_t)k * 4096)[t + c * 256];
            reinterpret_cast<float4*>(Wk)[t + c * 256] = v;
        }
        __syncthreads();
        float s = 0.f;
        #pragma unroll
        for (int j = 0; j < 64; ++j) s += Wk[il * 64 + j] * srcs[eg][j];
        acc += bnds[eg][k] * s;
    }
    out[(size_t)e * DIM + il] = acc;
}

extern "C" void kernel_launch(void* const* d_in, const int* in_sizes, int n_in,
                              void* d_out, int out_size, void* d_ws, size_t ws_size,
                              hipStream_t stream) {
    const float* atom = (const float*)d_in[0];   // (32,256,64) f32
    const float* bond = (const float*)d_in[1];   // (32,512,64) f32
    const int*   conn = (const int*)d_in[2];     // (32,512,2) int32 (narrowed)
    const float* bt   = (const float*)d_in[3];   // (64,4096) f32
    float* out = (float*)d_out;                  // (32,512,64) f32

    if (ws_size >= (size_t)64 * 4096 * sizeof(f16)) {
        f16* w2f = (f16*)d_ws;                   // 512 KB scratch
        prep_w2f<<<128, 256, 0, stream>>>(bt, w2f);
        // R9 measurement: launch bond_msg 3x (idempotent -> identical output).
        // Delta vs R7 total = 2 x (hot bond_msg + launch gap).
        bond_msg<<<256, 512, 0, stream>>>(atom, bond, conn, w2f, out);
        bond_msg<<<256, 512, 0, stream>>>(atom, bond, conn, w2f, out);
        bond_msg<<<256, 512, 0, stream>>>(atom, bond, conn, w2f, out);
    } else {
        bond_fallback<<<4096, 256, 0, stream>>>(atom, bond, conn, bt, out);
    }
}

// Round 10
// 23.539 us; speedup vs baseline: 25.2073x; 2.1890x over previous
//
#include <hip/hip_runtime.h>
#include <stdint.h>

// ---------------------------------------------------------------------------
// BondMatrixMessage: messages[b,e,i] = sum_{k,j} bond[b,e,k] W[k,i,j] src[b,e,j]
// GEMM recast: C[16384 x 64] = A[16384 x 4096] @ W2[4096 x 64]
//   A[e, k*64+j] = bond[e,k]*src[e,j]  (registers, v_pk_mul_f16)
//   W2 prep-cast to f16 in MFMA-fragment order (w2f) by prep kernel.
// R10: R9 measured hot bond_msg ~= 12-13 us even with w2f L2-resident, at
// only 42 GB/s/CU -> internal stall, not memory BW. R7's VGPR_Count=128 is
// EXACTLY the __launch_bounds__(512,2) cap; live state needs ~150+ regs ->
// compiler serializes ds_reads/spills. LDS (128KB) already limits to
// 1 block/CU, so (512,1) loses nothing and doubles the cap to 256.
// Also: A-gen (register-only) moved BEFORE the vmcnt wait so it hides under
// the load stall instead of being pinned after it by sched_barrier(0).
// conn is int32 (harness narrows int64): src idx = conn[e*2].
// ---------------------------------------------------------------------------

#define NATOMS 256
#define DIM 64
#define BM 64

typedef _Float16 f16;
typedef _Float16 f16x2 __attribute__((ext_vector_type(2)));
typedef _Float16 f16x8 __attribute__((ext_vector_type(8)));
typedef float f32x16 __attribute__((ext_vector_type(16)));

#define AS1 __attribute__((address_space(1)))
#define AS3 __attribute__((address_space(3)))

union H8 { f16x8 v8; f16x2 v2[4]; };

static __device__ __forceinline__ void gll16(const void* g, void* l) {
    __builtin_amdgcn_global_load_lds((AS1 void*)(uintptr_t)g, (AS3 void*)l, 16, 0, 0);
}

// prep: cast + permute bt (64 x 4096 f32) into fragment-ordered f16 chunks.
// Chunk (kg, wc, s, l): bt[kg][i*64 + u*8 .. +8], i=(l&31)+32*wc, u=2*s+(l>>5).
__global__ __launch_bounds__(256) void prep_w2f(const float* __restrict__ bt,
                                                f16* __restrict__ w2f) {
    const int d  = blockIdx.x * 256 + threadIdx.x;   // 32768 chunks
    const int kg = d >> 9, c = d & 511;
    const int wcq = c >> 8, s = (c >> 6) & 3, l = c & 63;
    const int i = (l & 31) + 32 * wcq;
    const int u = 2 * s + (l >> 5);
    const float* src = bt + (size_t)kg * 4096 + i * 64 + u * 8;
    const float4 p = *reinterpret_cast<const float4*>(src);
    const float4 q = *reinterpret_cast<const float4*>(src + 4);
    const f16x8 h = { (f16)p.x, (f16)p.y, (f16)p.z, (f16)p.w,
                      (f16)q.x, (f16)q.y, (f16)q.z, (f16)q.w };
    reinterpret_cast<f16x8*>(w2f)[d] = h;
}

static __device__ __forceinline__ unsigned swz16(unsigned lane) {
    // 16B-granular XOR swizzle for the epilogue partial buffer.
    return (lane * 16u) ^ ((lane & 0x38u) << 1);
}

__global__ __launch_bounds__(512, 1) void bond_msg(
    const float* __restrict__ atom, const float* __restrict__ bond,
    const int* __restrict__ conn, const f16* __restrict__ w2f,
    float* __restrict__ out)
{
    // LDS: main loop: [w*16K, w*16K+16K) = wave w's 4 x 4KB stage buffers.
    //      epilogue (after barrier): [w*8K, w*8K+8K) partials, swizzled.
    __shared__ __align__(16) unsigned char smem[131072];

    const int tid  = threadIdx.x;
    const int lane = tid & 63;
    const int w    = tid >> 6;     // wave 0..7
    const int wc   = w & 1;        // column half (i: 0-31 / 32-63)
    const int kq   = w >> 1;       // k quarter (16 k-values each)
    const int lo   = lane & 31;
    const int hi   = lane >> 5;
    const int blk  = blockIdx.x;
    const int bond0 = blk * BM;    // 8 blocks per batch; never straddles

    // ---- prologue global loads (issue early; conversions wait only these)
    const int m0 = lo, m1 = lo + 32;
    const int ia0 = conn[(bond0 + m0) * 2];
    const int ia1 = conn[(bond0 + m1) * 2];

    const char* gw = reinterpret_cast<const char*>(w2f)
                   + (size_t)(kq * 16) * 8192 + wc * 4096 + lane * 16;
    char* lsta = reinterpret_cast<char*>(smem) + w * 16384;          // uniform
    const char* lread = reinterpret_cast<const char*>(smem) + w * 16384 + lane * 16;

    #define ISSUE(itf) do {                                               \
        const char* _g = gw + (itf) * 8192;                               \
        char* _l = lsta + ((itf) & 3) * 4096;                             \
        gll16(_g,        _l);                                             \
        gll16(_g + 1024, _l + 1024);                                      \
        gll16(_g + 2048, _l + 2048);                                      \
        gll16(_g + 3072, _l + 3072);                                      \
    } while (0)

    // start the stage pipeline immediately (independent of everything else)
    ISSUE(0); ISSUE(1); ISSUE(2);

    // ---- bond k-slices -> dup'd f16 pairs in registers
    f16x2 bp0[16], bp1[16];
    {
        const float* br0 = bond + (size_t)(bond0 + m0) * DIM + kq * 16;
        const float* br1 = bond + (size_t)(bond0 + m1) * DIM + kq * 16;
        #pragma unroll
        for (int q = 0; q < 4; ++q) {
            const float4 v0 = *reinterpret_cast<const float4*>(br0 + q * 4);
            const float4 v1 = *reinterpret_cast<const float4*>(br1 + q * 4);
            const f16 a0 = (f16)v0.x, a1 = (f16)v0.y, a2 = (f16)v0.z, a3 = (f16)v0.w;
            const f16 c0 = (f16)v1.x, c1 = (f16)v1.y, c2 = (f16)v1.z, c3 = (f16)v1.w;
            bp0[q*4+0] = (f16x2){a0,a0}; bp0[q*4+1] = (f16x2){a1,a1};
            bp0[q*4+2] = (f16x2){a2,a2}; bp0[q*4+3] = (f16x2){a3,a3};
            bp1[q*4+0] = (f16x2){c0,c0}; bp1[q*4+1] = (f16x2){c1,c1};
            bp1[q*4+2] = (f16x2){c2,c2}; bp1[q*4+3] = (f16x2){c3,c3};
        }
    }

    // ---- src atom gather -> registers (f16 pairs)
    const float* ar0 = atom + (size_t)(blk >> 3) * (NATOMS * DIM) + (size_t)ia0 * DIM;
    const float* ar1 = atom + (size_t)(blk >> 3) * (NATOMS * DIM) + (size_t)ia1 * DIM;
    f16x2 srcv[2][4][4];   // [m-frag][s][pair]; j = s*16 + hi*8 + {0..7}
    #pragma unroll
    for (int s = 0; s < 4; ++s) {
        const int j0 = s * 16 + hi * 8;
        float4 p0 = *reinterpret_cast<const float4*>(ar0 + j0);
        float4 p1 = *reinterpret_cast<const float4*>(ar0 + j0 + 4);
        float4 q0 = *reinterpret_cast<const float4*>(ar1 + j0);
        float4 q1 = *reinterpret_cast<const float4*>(ar1 + j0 + 4);
        srcv[0][s][0] = (f16x2){ (f16)p0.x, (f16)p0.y };
        srcv[0][s][1] = (f16x2){ (f16)p0.z, (f16)p0.w };
        srcv[0][s][2] = (f16x2){ (f16)p1.x, (f16)p1.y };
        srcv[0][s][3] = (f16x2){ (f16)p1.z, (f16)p1.w };
        srcv[1][s][0] = (f16x2){ (f16)q0.x, (f16)q0.y };
        srcv[1][s][1] = (f16x2){ (f16)q0.z, (f16)q0.w };
        srcv[1][s][2] = (f16x2){ (f16)q1.x, (f16)q1.y };
        srcv[1][s][3] = (f16x2){ (f16)q1.z, (f16)q1.w };
    }

    // ---- main loop: 16 fully-unrolled steps, per-wave counted vmcnt.
    // Order inside a step: issue prefetch, A-GEN (register-only, hides under
    // the load stall), THEN the counted wait, then ds_read + MFMA.
    f32x16 acc0 = {}, acc1 = {};

    #define STEP(iti, wtxt) do {                                          \
        if ((iti) + 3 < 16) ISSUE((iti) + 3);                             \
        H8 _af0[4], _af1[4];                                              \
        {                                                                 \
            const f16x2 _c0 = bp0[iti];                                   \
            const f16x2 _c1 = bp1[iti];                                   \
            _Pragma("unroll")                                             \
            for (int s = 0; s < 4; ++s) {                                 \
                _Pragma("unroll")                                         \
                for (int t = 0; t < 4; ++t) {                             \
                    _af0[s].v2[t] = _c0 * srcv[0][s][t];                  \
                    _af1[s].v2[t] = _c1 * srcv[1][s][t];                  \
                }                                                         \
            }                                                             \
        }                                                                 \
        asm volatile("s_waitcnt vmcnt(" wtxt ")" ::: "memory");           \
        __builtin_amdgcn_sched_barrier(0);                                \
        {                                                                 \
            const char* _lr = lread + ((iti) & 3) * 4096;                 \
            _Pragma("unroll")                                             \
            for (int s = 0; s < 4; ++s) {                                 \
                const f16x8 bf = *reinterpret_cast<const f16x8*>(_lr + s * 1024); \
                acc0 = __builtin_amdgcn_mfma_f32_32x32x16_f16(_af0[s].v8, bf, acc0, 0, 0, 0); \
                acc1 = __builtin_amdgcn_mfma_f32_32x32x16_f16(_af1[s].v8, bf, acc1, 0, 0, 0); \
            }                                                             \
        }                                                                 \
    } while (0)

    STEP( 0, "12"); STEP( 1, "12"); STEP( 2, "12"); STEP( 3, "12");
    STEP( 4, "12"); STEP( 5, "12"); STEP( 6, "12"); STEP( 7, "12");
    STEP( 8, "12"); STEP( 9, "12"); STEP(10, "12"); STEP(11, "12");
    STEP(12, "12"); STEP(13, "8");  STEP(14, "4");  STEP(15, "0");

    #undef STEP
    #undef ISSUE

    // ---- epilogue: barrier (LDS reuse), all waves store partials
    // (swizzled, conflict-free), barrier, 512-thread parallel reduce+write.
    __syncthreads();
    {
        const unsigned wbase = (unsigned)w * 8192u;
        const unsigned so = swz16((unsigned)lane);
        #pragma unroll
        for (int g = 0; g < 4; ++g) {
            float4 v0 = { acc0[4*g+0], acc0[4*g+1], acc0[4*g+2], acc0[4*g+3] };
            *reinterpret_cast<float4*>(smem + wbase + g*1024 + so) = v0;
            float4 v1 = { acc1[4*g+0], acc1[4*g+1], acc1[4*g+2], acc1[4*g+3] };
            *reinterpret_cast<float4*>(smem + wbase + (g+4)*1024 + so) = v1;
        }
    }
    __syncthreads();
    {
        // thread t: column c = t&63, row group rb = t>>6 -> rows 32a+8g+{0..7}
        const int c  = tid & 63;
        const int rb = tid >> 6;
        const int a  = rb >> 2, g = rb & 3;
        const unsigned colb = (unsigned)(c & 31);
        const unsigned wcs  = (unsigned)(c >> 5);
        const unsigned o0 = swz16(colb);        // hi=0 lane = colb
        const unsigned o1 = swz16(32u + colb);  // hi=1 lane
        float4 s0 = {0.f,0.f,0.f,0.f}, s1 = {0.f,0.f,0.f,0.f};
        #pragma unroll
        for (int q = 0; q < 4; ++q) {
            const unsigned base = (unsigned)((q*2 + wcs) * 8192 + (a*4+g) * 1024);
            const float4 u0 = *reinterpret_cast<const float4*>(smem + base + o0);
            const float4 u1 = *reinterpret_cast<const float4*>(smem + base + o1);
            s0.x += u0.x; s0.y += u0.y; s0.z += u0.z; s0.w += u0.w;
            s1.x += u1.x; s1.y += u1.y; s1.z += u1.z; s1.w += u1.w;
        }
        float* orow = out + (size_t)(bond0 + 32*a + 8*g) * 64 + c;
        orow[0*64] = s0.x; orow[1*64] = s0.y; orow[2*64] = s0.z; orow[3*64] = s0.w;
        orow[4*64] = s1.x; orow[5*64] = s1.y; orow[6*64] = s1.z; orow[7*64] = s1.w;
    }
}

// ---- fallback (ws too small): f32, LDS-staged, correct.
__global__ __launch_bounds__(256) void bond_fallback(
    const float* __restrict__ atom, const float* __restrict__ bond,
    const int* __restrict__ conn, const float* __restrict__ bt,
    float* __restrict__ out)
{
    __shared__ float Wk[4096];
    __shared__ float srcs[4][64];
    __shared__ float bnds[4][64];
    const int blk = blockIdx.x;
    const int e0 = blk * 4;
    const int b = e0 >> 9;
    const int t = threadIdx.x;
    const int il = t & 63, eg = t >> 6;
    const int e = e0 + eg;
    const int ia = conn[e * 2];
    srcs[eg][il] = atom[(size_t)b * (NATOMS * DIM) + (size_t)ia * DIM + il];
    bnds[eg][il] = bond[(size_t)e * DIM + il];
    float acc = 0.f;
    for (int k = 0; k < 64; ++k) {
        __syncthreads();
        #pragma unroll
        for (int c = 0; c < 4; ++c) {
            float4 v = reinterpret_cast<const float4*>(bt + (size_t)k * 4096)[t + c * 256];
            reinterpret_cast<float4*>(Wk)[t + c * 256] = v;
        }
        __syncthreads();
        float s = 0.f;
        #pragma unroll
        for (int j = 0; j < 64; ++j) s += Wk[il * 64 + j] * srcs[eg][j];
        acc += bnds[eg][k] * s;
    }
    out[(size_t)e * DIM + il] = acc;
}

extern "C" void kernel_launch(void* const* d_in, const int* in_sizes, int n_in,
                              void* d_out, int out_size, void* d_ws, size_t ws_size,
                              hipStream_t stream) {
    const float* atom = (const float*)d_in[0];   // (32,256,64) f32
    const float* bond = (const float*)d_in[1];   // (32,512,64) f32
    const int*   conn = (const int*)d_in[2];     // (32,512,2) int32 (narrowed)
    const float* bt   = (const float*)d_in[3];   // (64,4096) f32
    float* out = (float*)d_out;                  // (32,512,64) f32

    if (ws_size >= (size_t)64 * 4096 * sizeof(f16)) {
        f16* w2f = (f16*)d_ws;                   // 512 KB scratch
        prep_w2f<<<128, 256, 0, stream>>>(bt, w2f);
        bond_msg<<<256, 512, 0, stream>>>(atom, bond, conn, w2f, out);
    } else {
        bond_fallback<<<4096, 256, 0, stream>>>(atom, bond, conn, bt, out);
    }
}